// Round 1
// baseline (997.554 us; speedup 1.0000x reference)
//
#include <hip/hip_runtime.h>
#include <hip/hip_bf16.h>
#include <math.h>

// ---------------- problem constants ----------------
#define B_ROWS 4096
#define DZ     2048
#define DE     128
#define M_EXP  32
#define H_DIM  1024
#define NBIG   32768          // M_EXP * H_DIM
#define NEXTRA 256            // 128 gate + 3 base + 125 zero-pad
#define NTOT   (NBIG + NEXTRA)   // 33024 = 258 * 128
#define W1_LD  (DZ + DE)      // 2176

typedef _Float16 half8 __attribute__((ext_vector_type(8)));
typedef float    f32x4 __attribute__((ext_vector_type(4)));

#define AS1 __attribute__((address_space(1)))
#define AS3 __attribute__((address_space(3)))

__device__ __forceinline__ void async_copy16(const void* g, void* l) {
  __builtin_amdgcn_global_load_lds((const AS1 void*)g, (AS3 void*)l, 16, 0, 0);
}

__device__ __forceinline__ half8 cvt8(const float4& a, const float4& b) {
  half8 h = {(_Float16)a.x, (_Float16)a.y, (_Float16)a.z, (_Float16)a.w,
             (_Float16)b.x, (_Float16)b.y, (_Float16)b.z, (_Float16)b.w};
  return h;
}

// ---------------- z -> f16 ----------------
__global__ __launch_bounds__(256) void k_cvt_z(const float* __restrict__ z,
                                               _Float16* __restrict__ zh) {
  long i = ((long)blockIdx.x * 256 + threadIdx.x) * 8;
  float4 a = *(const float4*)(z + i);
  float4 b = *(const float4*)(z + i + 4);
  *(half8*)(zh + i) = cvt8(a, b);
}

// ---------------- W1 z-part -> f16 packed rows; tail -> hbias = E.W1e + b1 ----------------
__global__ __launch_bounds__(256) void k_cvt_w1(const float* __restrict__ W1,
                                                const float* __restrict__ E,
                                                const float* __restrict__ b1,
                                                _Float16* __restrict__ W1h,
                                                float* __restrict__ hbias) {
  const long n = blockIdx.x;        // 0..32767  (n = m*1024 + h)
  const int  t = threadIdx.x;       // 256
  const float* src = W1 + n * W1_LD;
  float4 a = *(const float4*)(src + t * 8);
  float4 b = *(const float4*)(src + t * 8 + 4);
  *(half8*)(W1h + n * DZ + t * 8) = cvt8(a, b);
  if (t < 32) {
    int m = (int)(n >> 10);
    float4 w = *(const float4*)(src + DZ + t * 4);
    float4 e = *(const float4*)(E + m * DE + t * 4);
    float p = w.x * e.x + w.y * e.y + w.z * e.z + w.w * e.w;
    p += __shfl_xor(p, 16);
    p += __shfl_xor(p, 8);
    p += __shfl_xor(p, 4);
    p += __shfl_xor(p, 2);
    p += __shfl_xor(p, 1);
    if (t == 0) hbias[n] = p + b1[n];
  }
}

// ---------------- gate_W / base_W -> f16 rows appended after NBIG; pad rows zeroed ----------------
__global__ __launch_bounds__(256) void k_cvt_small(const float* __restrict__ gate_W,
                                                   const float* __restrict__ base_W,
                                                   _Float16* __restrict__ W1h) {
  int r = blockIdx.x;               // 0..255
  int t = threadIdx.x;
  const float* src = nullptr;
  if (r < 128)       src = gate_W + (long)r * DZ;
  else if (r < 131)  src = base_W + (long)(r - 128) * DZ;
  _Float16* dst = W1h + (long)(NBIG + r) * DZ + t * 8;
  if (src) {
    float4 a = *(const float4*)(src + t * 8);
    float4 b = *(const float4*)(src + t * 8 + 4);
    *(half8*)dst = cvt8(a, b);
  } else {
    half8 zv = {(_Float16)0, (_Float16)0, (_Float16)0, (_Float16)0,
                (_Float16)0, (_Float16)0, (_Float16)0, (_Float16)0};
    *(half8*)dst = zv;
  }
}

// ---------------- fused GEMM: C = zh (4096x2048) * W1h^T (33024x2048) ----------------
// delta tiles (tN<256): GELU(C+hbias) dot W2 -> atomicAdd into L
// raw tiles (tN>=256): write C to qraw (gate + base pre-activations)
__global__ __launch_bounds__(256) void k_gemm(const _Float16* __restrict__ A,   // zh
                                              const _Float16* __restrict__ Bm,  // W1h
                                              const float* __restrict__ hbias,  // [NBIG]
                                              const float* __restrict__ W2,     // [M,3,H]
                                              float* __restrict__ Lout,         // [B,96] (atomic)
                                              float* __restrict__ qraw) {       // [B,256]
  __shared__ __align__(16) _Float16 As[128 * 32];
  __shared__ __align__(16) _Float16 Bs[128 * 32];

  // XCD-aware swizzle: 8256 blocks, 8256/8 = 1032 per XCD (bijective)
  int flat = blockIdx.y * gridDim.x + blockIdx.x;
  int wg   = (flat & 7) * 1032 + (flat >> 3);
  const int tN = wg % 258;
  const int tM = wg / 258;

  const int tid = threadIdx.x;
  const int w   = tid >> 6;          // wave 0..3
  const int l   = tid & 63;
  const int wr  = w >> 1;            // 2x2 waves, each 64x64 out
  const int wc  = w & 1;

  f32x4 zero4 = {0.f, 0.f, 0.f, 0.f};
  f32x4 acc[4][4];
#pragma unroll
  for (int i = 0; i < 4; ++i)
#pragma unroll
    for (int j = 0; j < 4; ++j) acc[i][j] = zero4;

  const long baseA = (long)tM * 128 * DZ;
  const long baseB = (long)tN * 128 * DZ;

  for (int kt = 0; kt < DZ / 32; ++kt) {
#pragma unroll
    for (int r = 0; r < 2; ++r) {
      int c   = r * 256 + tid;       // 16B chunk id, 0..511
      int row = c >> 2;
      int q   = c & 3;
      const _Float16* ga = A  + baseA + (long)row * DZ + kt * 32 + q * 8;
      async_copy16(ga, &As[c * 8]);
      const _Float16* gb = Bm + baseB + (long)row * DZ + kt * 32 + q * 8;
      async_copy16(gb, &Bs[c * 8]);
    }
    __syncthreads();

    half8 af[4], bf[4];
#pragma unroll
    for (int i = 0; i < 4; ++i)
      af[i] = *(const half8*)&As[(wr * 64 + i * 16 + (l & 15)) * 32 + (l >> 4) * 8];
#pragma unroll
    for (int j = 0; j < 4; ++j)
      bf[j] = *(const half8*)&Bs[(wc * 64 + j * 16 + (l & 15)) * 32 + (l >> 4) * 8];

#pragma unroll
    for (int i = 0; i < 4; ++i)
#pragma unroll
      for (int j = 0; j < 4; ++j)
        acc[i][j] = __builtin_amdgcn_mfma_f32_16x16x32_f16(af[i], bf[j], acc[i][j], 0, 0, 0);
    __syncthreads();
  }

  const int colbase = tN * 128 + wc * 64;
  if (tN < 256) {
    const int m = tN >> 3;           // 8 tiles per expert
    float w2v[3][4];
    float hb[4];
#pragma unroll
    for (int j = 0; j < 4; ++j) {
      int col = colbase + j * 16 + (l & 15);
      int hh  = col & (H_DIM - 1);
      hb[j] = hbias[col];
#pragma unroll
      for (int o = 0; o < 3; ++o) w2v[o][j] = W2[((long)m * 3 + o) * H_DIM + hh];
    }
#pragma unroll
    for (int i = 0; i < 4; ++i) {
      int row = tM * 128 + wr * 64 + i * 16 + (l >> 4) * 4;
#pragma unroll
      for (int r = 0; r < 4; ++r) {
        float hv[4];
#pragma unroll
        for (int j = 0; j < 4; ++j) {
          float x = acc[i][j][r] + hb[j];
          hv[j] = 0.5f * x * (1.0f + erff(x * 0.70710678118654752f));  // exact gelu
        }
#pragma unroll
        for (int o = 0; o < 3; ++o) {
          float p = hv[0] * w2v[o][0] + hv[1] * w2v[o][1] + hv[2] * w2v[o][2] + hv[3] * w2v[o][3];
          p += __shfl_xor(p, 1);
          p += __shfl_xor(p, 2);
          p += __shfl_xor(p, 4);
          p += __shfl_xor(p, 8);
          if ((l & 15) == o) atomicAdd(&Lout[(long)(row + r) * 96 + m * 3 + o], p);
        }
      }
    }
  } else {
    // raw gate/base pre-activations
#pragma unroll
    for (int i = 0; i < 4; ++i) {
      int row = tM * 128 + wr * 64 + i * 16 + (l >> 4) * 4;
#pragma unroll
      for (int r = 0; r < 4; ++r) {
#pragma unroll
        for (int j = 0; j < 4; ++j) {
          int col = colbase + j * 16 + (l & 15) - NBIG;  // 0..255
          qraw[(long)(row + r) * 256 + col] = acc[i][j][r];
        }
      }
    }
  }
}

// ---------------- post: q normalize, sims, L += base + b2 ----------------
__global__ __launch_bounds__(128) void k_post(const float* __restrict__ qraw,
                                              const float* __restrict__ gate_b,
                                              const float* __restrict__ base_b,
                                              const float* __restrict__ E,
                                              const float* __restrict__ b2,
                                              float* __restrict__ out) {
  const int b = blockIdx.x;
  const int t = threadIdx.x;          // 128
  __shared__ float qs[DE];
  __shared__ float invE[M_EXP];
  __shared__ float wsum[2];
  __shared__ float pA[M_EXP], pB[M_EXP];

  if (t < 32) {
    float ss = 0.f;
    const float* er = E + t * DE;
    for (int e = 0; e < DE; ++e) { float v = er[e]; ss += v * v; }
    invE[t] = 1.0f / fmaxf(sqrtf(ss), 1e-12f);
  }

  float val = qraw[(long)b * 256 + t] + gate_b[t];
  float ss = val * val;
  ss += __shfl_xor(ss, 1);  ss += __shfl_xor(ss, 2);  ss += __shfl_xor(ss, 4);
  ss += __shfl_xor(ss, 8);  ss += __shfl_xor(ss, 16); ss += __shfl_xor(ss, 32);
  if ((t & 63) == 0) wsum[t >> 6] = ss;
  __syncthreads();
  float inv = 1.0f / fmaxf(sqrtf(wsum[0] + wsum[1]), 1e-12f);
  qs[t] = val * inv;
  __syncthreads();

  {
    int m = t & 31, hf = t >> 5;
    const float* er = E + m * DE + hf * 32;
    const float* qq = qs + hf * 32;
    float p = 0.f;
#pragma unroll
    for (int e = 0; e < 32; ++e) p += qq[e] * er[e];
    p += __shfl_xor(p, 32);
    if (t < 32) pA[m] = p;
    else if (t >= 64 && t < 96) pB[m] = p;
    __syncthreads();
    if (t < 32) out[(long)B_ROWS * 96 + (long)b * 32 + t] = (pA[t] + pB[t]) * invE[t];
  }

  if (t < 96) {
    int o = t % 3;
    float bv = qraw[(long)b * 256 + 128 + o] + base_b[o];
    out[(long)b * 96 + t] += bv + b2[t];
  }
}

// ---------------- launch ----------------
extern "C" void kernel_launch(void* const* d_in, const int* in_sizes, int n_in,
                              void* d_out, int out_size, void* d_ws, size_t ws_size,
                              hipStream_t stream) {
  const float* z      = (const float*)d_in[0];
  const float* base_W = (const float*)d_in[1];
  const float* base_b = (const float*)d_in[2];
  const float* gate_W = (const float*)d_in[3];
  const float* gate_b = (const float*)d_in[4];
  const float* E      = (const float*)d_in[5];
  const float* W1     = (const float*)d_in[6];
  const float* b1     = (const float*)d_in[7];
  const float* W2     = (const float*)d_in[8];
  const float* b2     = (const float*)d_in[9];
  float* out = (float*)d_out;

  char* ws = (char*)d_ws;
  const size_t off_zh    = 0;                                   // B*DZ*2      = 16,777,216
  const size_t off_w1h   = off_zh  + (size_t)B_ROWS * DZ * 2;   // NTOT*DZ*2   = 135,266,304
  const size_t off_hbias = off_w1h + (size_t)NTOT * DZ * 2;     // NBIG*4      = 131,072
  const size_t off_qraw  = off_hbias + (size_t)NBIG * 4;        // B*256*4     = 4,194,304
  _Float16* zh    = (_Float16*)(ws + off_zh);
  _Float16* W1h   = (_Float16*)(ws + off_w1h);
  float*    hbias = (float*)(ws + off_hbias);
  float*    qraw  = (float*)(ws + off_qraw);

  // L must start at 0 every call (epilogue atomically accumulates into it)
  hipMemsetAsync(d_out, 0, (size_t)B_ROWS * 96 * sizeof(float), stream);

  k_cvt_z<<<(B_ROWS * DZ) / (256 * 8), 256, 0, stream>>>(z, zh);
  k_cvt_w1<<<NBIG, 256, 0, stream>>>(W1, E, b1, W1h, hbias);
  k_cvt_small<<<NEXTRA, 256, 0, stream>>>(gate_W, base_W, W1h);
  k_gemm<<<dim3(NTOT / 128, B_ROWS / 128), 256, 0, stream>>>(zh, W1h, hbias, W2, out, qraw);
  k_post<<<B_ROWS, 128, 0, stream>>>(qraw, gate_b, base_b, E, b2, out);
}

// Round 2
// 938.844 us; speedup vs baseline: 1.0625x; 1.0625x over previous
//
#include <hip/hip_runtime.h>
#include <hip/hip_bf16.h>
#include <math.h>

// ---------------- problem constants ----------------
#define B_ROWS 4096
#define DZ     2048
#define DE     128
#define M_EXP  32
#define H_DIM  1024
#define NBIG   32768          // M_EXP * H_DIM
#define NEXTRA 256            // 128 gate + 3 base + 125 zero-pad
#define NTOT   (NBIG + NEXTRA)   // 33024 = 129 * 256
#define W1_LD  (DZ + DE)      // 2176

typedef _Float16 half8 __attribute__((ext_vector_type(8)));
typedef float    f32x4 __attribute__((ext_vector_type(4)));

#define AS1 __attribute__((address_space(1)))
#define AS3 __attribute__((address_space(3)))

__device__ __forceinline__ void async_copy16(const void* g, void* l) {
  __builtin_amdgcn_global_load_lds((const AS1 void*)g, (AS3 void*)l, 16, 0, 0);
}

__device__ __forceinline__ half8 cvt8(const float4& a, const float4& b) {
  half8 h = {(_Float16)a.x, (_Float16)a.y, (_Float16)a.z, (_Float16)a.w,
             (_Float16)b.x, (_Float16)b.y, (_Float16)b.z, (_Float16)b.w};
  return h;
}

// ---------------- z -> f16 ----------------
__global__ __launch_bounds__(256) void k_cvt_z(const float* __restrict__ z,
                                               _Float16* __restrict__ zh) {
  long i = ((long)blockIdx.x * 256 + threadIdx.x) * 8;
  float4 a = *(const float4*)(z + i);
  float4 b = *(const float4*)(z + i + 4);
  *(half8*)(zh + i) = cvt8(a, b);
}

// ---------------- W1 z-part -> f16 packed rows; tail -> hbias = E.W1e + b1 ----------------
__global__ __launch_bounds__(256) void k_cvt_w1(const float* __restrict__ W1,
                                                const float* __restrict__ E,
                                                const float* __restrict__ b1,
                                                _Float16* __restrict__ W1h,
                                                float* __restrict__ hbias) {
  const long n = blockIdx.x;        // 0..32767  (n = m*1024 + h)
  const int  t = threadIdx.x;       // 256
  const float* src = W1 + n * W1_LD;
  float4 a = *(const float4*)(src + t * 8);
  float4 b = *(const float4*)(src + t * 8 + 4);
  *(half8*)(W1h + n * DZ + t * 8) = cvt8(a, b);
  if (t < 32) {
    int m = (int)(n >> 10);
    float4 w = *(const float4*)(src + DZ + t * 4);
    float4 e = *(const float4*)(E + m * DE + t * 4);
    float p = w.x * e.x + w.y * e.y + w.z * e.z + w.w * e.w;
    p += __shfl_xor(p, 16);
    p += __shfl_xor(p, 8);
    p += __shfl_xor(p, 4);
    p += __shfl_xor(p, 2);
    p += __shfl_xor(p, 1);
    if (t == 0) hbias[n] = p + b1[n];
  }
}

// ---------------- gate_W / base_W -> f16 rows appended after NBIG; pad rows zeroed ----------------
__global__ __launch_bounds__(256) void k_cvt_small(const float* __restrict__ gate_W,
                                                   const float* __restrict__ base_W,
                                                   _Float16* __restrict__ W1h) {
  int r = blockIdx.x;               // 0..255
  int t = threadIdx.x;
  const float* src = nullptr;
  if (r < 128)       src = gate_W + (long)r * DZ;
  else if (r < 131)  src = base_W + (long)(r - 128) * DZ;
  _Float16* dst = W1h + (long)(NBIG + r) * DZ + t * 8;
  if (src) {
    float4 a = *(const float4*)(src + t * 8);
    float4 b = *(const float4*)(src + t * 8 + 4);
    *(half8*)dst = cvt8(a, b);
  } else {
    half8 zv = {(_Float16)0, (_Float16)0, (_Float16)0, (_Float16)0,
                (_Float16)0, (_Float16)0, (_Float16)0, (_Float16)0};
    *(half8*)dst = zv;
  }
}

// ============ 256x256 8-phase GEMM: C = zh (4096x2048) * W1h^T (33024x2048) ============
// 8 waves (2Mx4N), each 128x64 out. BK=64, 2 K-tiles/iter, 8 phases/iter.
// LDS 128 KiB double-buffered, XOR-swizzled 16B granules (g ^= row&7).
// vmcnt(2) only at phases 4 and 8. setprio(1) around MFMA clusters.
__global__ __launch_bounds__(512, 2) void k_gemm256(const _Float16* __restrict__ A,   // zh
                                                    const _Float16* __restrict__ Bm,  // W1h
                                                    const float* __restrict__ hbias,  // [NBIG]
                                                    const float* __restrict__ W2,     // [M,3,H]
                                                    float* __restrict__ Lout,         // [B,96] atomic
                                                    float* __restrict__ qraw) {       // [B,256]
  __shared__ _Float16 sm[2][2][16384];   // [buf][A/B][256 rows x 64 cols], 131072 B

  // XCD-aware bijective swizzle: 2064 blocks = 8 * 258
  int flat = blockIdx.y * gridDim.x + blockIdx.x;
  int wg   = (flat & 7) * 258 + (flat >> 3);
  const int tN = wg % 129;
  const int tM = wg / 129;

  const int tid = threadIdx.x;
  const int w  = tid >> 6, l = tid & 63;
  const int wm = w >> 2, wn = w & 3;        // wave grid 2x4
  const int rl = l & 15, lg = l >> 4;

  // ---- staging constants (linear LDS dest, swizzled global src) ----
  const int q0 = w * 64 + l, q1 = 512 + q0;        // granule ids within a half-tile
  const int rr0 = q0 >> 3, rr1 = q1 >> 3;          // row within half (0..127)
  const int sw0 = ((q0 & 7) ^ (rr0 & 7)) * 8;      // swizzled k-granule -> elems
  const int sw1 = ((q1 & 7) ^ (rr1 & 7)) * 8;
  const _Float16* sA0 = A  + (long)(tM * 256 + rr0) * DZ + sw0;
  const _Float16* sA1 = A  + (long)(tM * 256 + rr1) * DZ + sw1;
  const _Float16* sB0 = Bm + (long)(tN * 256 + rr0) * DZ + sw0;
  const _Float16* sB1 = Bm + (long)(tN * 256 + rr1) * DZ + sw1;

#define STAGE_H(buf, ab, half, kt) do { \
    const _Float16* _s0 = ((ab) ? sB0 : sA0) + (half) * 128 * DZ + (kt) * 64; \
    const _Float16* _s1 = ((ab) ? sB1 : sA1) + (half) * 128 * DZ + (kt) * 64; \
    async_copy16(_s0, &sm[buf][ab][(half) * 8192 + q0 * 8]); \
    async_copy16(_s1, &sm[buf][ab][(half) * 8192 + q1 * 8]); \
  } while (0)
  // part: 0=(A,h0) 1=(A,h1) 2=(B,h0) 3=(B,h1)
#define STAGE_P(buf, kt, p) do { \
    if ((p) < 2) STAGE_H(buf, 0, (p) & 1, kt); else STAGE_H(buf, 1, (p) & 1, kt); } while (0)

  // ---- fragment-read constants (swizzled ds_read, bank-balanced) ----
  const int sg0 = (lg ^ (rl & 7)) * 8;             // kk=0
  const int sg1 = ((4 + lg) ^ (rl & 7)) * 8;       // kk=1
  const int arow = (wm * 128 + rl) * 64;
  const int brow = (wn * 64  + rl) * 64;

  half8 af[4][2], bf0[2][2], bf1[2][2];
  f32x4 acc[8][4];
  f32x4 z4 = {0.f, 0.f, 0.f, 0.f};
#pragma unroll
  for (int i = 0; i < 8; ++i)
#pragma unroll
    for (int j = 0; j < 4; ++j) acc[i][j] = z4;

#define LOAD_A(buf, qi) do { _Pragma("unroll") for (int ii = 0; ii < 4; ++ii) { \
    int _b = arow + ((qi) * 64 + ii * 16) * 64; \
    af[ii][0] = *(const half8*)&sm[buf][0][_b + sg0]; \
    af[ii][1] = *(const half8*)&sm[buf][0][_b + sg1]; } } while (0)

#define LOAD_B(dst, buf, jp) do { _Pragma("unroll") for (int jj = 0; jj < 2; ++jj) { \
    int _b = brow + ((jp) * 32 + jj * 16) * 64; \
    dst[jj][0] = *(const half8*)&sm[buf][1][_b + sg0]; \
    dst[jj][1] = *(const half8*)&sm[buf][1][_b + sg1]; } } while (0)

#define MFMA_Q(qi, jp, BF) do { __builtin_amdgcn_s_setprio(1); \
    _Pragma("unroll") for (int ii = 0; ii < 4; ++ii) \
    _Pragma("unroll") for (int jj = 0; jj < 2; ++jj) { \
      acc[(qi)*4+ii][(jp)*2+jj] = __builtin_amdgcn_mfma_f32_16x16x32_f16(af[ii][0], BF[jj][0], acc[(qi)*4+ii][(jp)*2+jj], 0, 0, 0); \
      acc[(qi)*4+ii][(jp)*2+jj] = __builtin_amdgcn_mfma_f32_16x16x32_f16(af[ii][1], BF[jj][1], acc[(qi)*4+ii][(jp)*2+jj], 0, 0, 0); } \
    __builtin_amdgcn_s_setprio(0); } while (0)

#define BAR() do { asm volatile("" ::: "memory"); __builtin_amdgcn_s_barrier(); asm volatile("" ::: "memory"); } while (0)
#define VMCNT(n) asm volatile("s_waitcnt vmcnt(" #n ")" ::: "memory")

  // ---- prologue: tile0 -> buf0 (4 parts), tile1 part0 -> buf1 ----
  STAGE_P(0, 0, 0); STAGE_P(0, 0, 1); STAGE_P(0, 0, 2); STAGE_P(0, 0, 3);
  STAGE_P(1, 1, 0);
  VMCNT(2);
  BAR();

  // ---- main loop: 16 iters x 2 K-tiles ----
  for (int n = 0; n < 16; ++n) {
    // P1: reads buf0 af(qi0)+bf0; stage buf1 part1
    LOAD_A(0, 0); LOAD_B(bf0, 0, 0);
    STAGE_P(1, 2 * n + 1, 1);
    BAR(); MFMA_Q(0, 0, bf0); BAR();
    // P2
    LOAD_B(bf1, 0, 1);
    STAGE_P(1, 2 * n + 1, 2);
    BAR(); MFMA_Q(0, 1, bf1); BAR();
    // P3 (last reads of buf0)
    LOAD_A(0, 1);
    STAGE_P(1, 2 * n + 1, 3);
    BAR(); MFMA_Q(1, 1, bf1); BAR();
    // P4: buf0 now dead -> start staging tile 2n+2; certify buf1 (tile 2n+1)
    if (n < 15) { STAGE_P(0, 2 * n + 2, 0); VMCNT(2); } else { VMCNT(0); }
    BAR(); MFMA_Q(1, 0, bf0); BAR();
    // P5: reads buf1
    LOAD_A(1, 0); LOAD_B(bf0, 1, 0);
    if (n < 15) STAGE_P(0, 2 * n + 2, 1);
    BAR(); MFMA_Q(0, 0, bf0); BAR();
    // P6
    LOAD_B(bf1, 1, 1);
    if (n < 15) STAGE_P(0, 2 * n + 2, 2);
    BAR(); MFMA_Q(0, 1, bf1); BAR();
    // P7 (last reads of buf1)
    LOAD_A(1, 1);
    if (n < 15) STAGE_P(0, 2 * n + 2, 3);
    BAR(); MFMA_Q(1, 1, bf1); BAR();
    // P8: buf1 dead -> stage tile 2n+3 part0; certify buf0 (tile 2n+2)
    if (n < 15) { STAGE_P(1, 2 * n + 3, 0); VMCNT(2); } else { VMCNT(0); }
    BAR(); MFMA_Q(1, 0, bf0); BAR();
  }

  // ---- epilogue ----
  const int lg4 = lg * 4;
  if (tN < 128) {
    const int m = tN >> 2;                 // 4 tiles per expert (1024 cols)
    const int colb = tN * 256 + wn * 64;
    float hb[4], w2v[3][4];
#pragma unroll
    for (int j = 0; j < 4; ++j) {
      int col = colb + j * 16 + rl;
      hb[j] = hbias[col];
      int hh = col & (H_DIM - 1);
#pragma unroll
      for (int o = 0; o < 3; ++o) w2v[o][j] = W2[((long)m * 3 + o) * H_DIM + hh];
    }
#pragma unroll
    for (int i = 0; i < 8; ++i) {
      int grow = tM * 256 + wm * 128 + i * 16 + lg4;
#pragma unroll
      for (int r = 0; r < 4; ++r) {
        float hv[4];
#pragma unroll
        for (int j = 0; j < 4; ++j) {
          float x = acc[i][j][r] + hb[j];
          hv[j] = 0.5f * x * (1.0f + erff(x * 0.70710678118654752f));  // exact gelu
        }
#pragma unroll
        for (int o = 0; o < 3; ++o) {
          float p = hv[0] * w2v[o][0] + hv[1] * w2v[o][1] + hv[2] * w2v[o][2] + hv[3] * w2v[o][3];
          p += __shfl_xor(p, 1);
          p += __shfl_xor(p, 2);
          p += __shfl_xor(p, 4);
          p += __shfl_xor(p, 8);
          if (rl == o) atomicAdd(&Lout[(long)(grow + r) * 96 + m * 3 + o], p);
        }
      }
    }
  } else {
    // raw gate/base pre-activations (cols 32768..33023)
#pragma unroll
    for (int i = 0; i < 8; ++i) {
      int grow = tM * 256 + wm * 128 + i * 16 + lg4;
#pragma unroll
      for (int r = 0; r < 4; ++r)
#pragma unroll
        for (int j = 0; j < 4; ++j) {
          int c = wn * 64 + j * 16 + rl;
          qraw[(long)(grow + r) * 256 + c] = acc[i][j][r];
        }
    }
  }
}

// ---------------- post: q normalize, sims, L += base + b2 ----------------
__global__ __launch_bounds__(128) void k_post(const float* __restrict__ qraw,
                                              const float* __restrict__ gate_b,
                                              const float* __restrict__ base_b,
                                              const float* __restrict__ E,
                                              const float* __restrict__ b2,
                                              float* __restrict__ out) {
  const int b = blockIdx.x;
  const int t = threadIdx.x;          // 128
  __shared__ float qs[DE];
  __shared__ float invE[M_EXP];
  __shared__ float wsum[2];
  __shared__ float pA[M_EXP], pB[M_EXP];

  if (t < 32) {
    float ss = 0.f;
    const float* er = E + t * DE;
    for (int e = 0; e < DE; ++e) { float v = er[e]; ss += v * v; }
    invE[t] = 1.0f / fmaxf(sqrtf(ss), 1e-12f);
  }

  float val = qraw[(long)b * 256 + t] + gate_b[t];
  float ss = val * val;
  ss += __shfl_xor(ss, 1);  ss += __shfl_xor(ss, 2);  ss += __shfl_xor(ss, 4);
  ss += __shfl_xor(ss, 8);  ss += __shfl_xor(ss, 16); ss += __shfl_xor(ss, 32);
  if ((t & 63) == 0) wsum[t >> 6] = ss;
  __syncthreads();
  float inv = 1.0f / fmaxf(sqrtf(wsum[0] + wsum[1]), 1e-12f);
  qs[t] = val * inv;
  __syncthreads();

  {
    int m = t & 31, hf = t >> 5;
    const float* er = E + m * DE + hf * 32;
    const float* qq = qs + hf * 32;
    float p = 0.f;
#pragma unroll
    for (int e = 0; e < 32; ++e) p += qq[e] * er[e];
    p += __shfl_xor(p, 32);
    if (t < 32) pA[m] = p;
    else if (t >= 64 && t < 96) pB[m] = p;
    __syncthreads();
    if (t < 32) out[(long)B_ROWS * 96 + (long)b * 32 + t] = (pA[t] + pB[t]) * invE[t];
  }

  if (t < 96) {
    int o = t % 3;
    float bv = qraw[(long)b * 256 + 128 + o] + base_b[o];
    out[(long)b * 96 + t] += bv + b2[t];
  }
}

// ---------------- launch ----------------
extern "C" void kernel_launch(void* const* d_in, const int* in_sizes, int n_in,
                              void* d_out, int out_size, void* d_ws, size_t ws_size,
                              hipStream_t stream) {
  const float* z      = (const float*)d_in[0];
  const float* base_W = (const float*)d_in[1];
  const float* base_b = (const float*)d_in[2];
  const float* gate_W = (const float*)d_in[3];
  const float* gate_b = (const float*)d_in[4];
  const float* E      = (const float*)d_in[5];
  const float* W1     = (const float*)d_in[6];
  const float* b1     = (const float*)d_in[7];
  const float* W2     = (const float*)d_in[8];
  const float* b2     = (const float*)d_in[9];
  float* out = (float*)d_out;

  char* ws = (char*)d_ws;
  const size_t off_zh    = 0;                                   // B*DZ*2
  const size_t off_w1h   = off_zh  + (size_t)B_ROWS * DZ * 2;   // NTOT*DZ*2
  const size_t off_hbias = off_w1h + (size_t)NTOT * DZ * 2;     // NBIG*4
  const size_t off_qraw  = off_hbias + (size_t)NBIG * 4;        // B*256*4
  _Float16* zh    = (_Float16*)(ws + off_zh);
  _Float16* W1h   = (_Float16*)(ws + off_w1h);
  float*    hbias = (float*)(ws + off_hbias);
  float*    qraw  = (float*)(ws + off_qraw);

  // L must start at 0 every call (epilogue atomically accumulates into it)
  hipMemsetAsync(d_out, 0, (size_t)B_ROWS * 96 * sizeof(float), stream);

  k_cvt_z<<<(B_ROWS * DZ) / (256 * 8), 256, 0, stream>>>(z, zh);
  k_cvt_w1<<<NBIG, 256, 0, stream>>>(W1, E, b1, W1h, hbias);
  k_cvt_small<<<NEXTRA, 256, 0, stream>>>(gate_W, base_W, W1h);
  k_gemm256<<<dim3(129, 16), 512, 0, stream>>>(zh, W1h, hbias, W2, out, qraw);
  k_post<<<B_ROWS, 128, 0, stream>>>(qraw, gate_b, base_b, E, b2, out);
}